// Round 24
// baseline (125.485 us; speedup 1.0000x reference)
//
#include <hip/hip_runtime.h>

static constexpr int SD = 21, HD = 64, LT = 14;
static constexpr int NFRAG = 40;     // 36 MLP frags + 4 head frags (fid 36-39)
static constexpr int ATS   = 20;     // at row stride in u32 (2-way-free reads; rows use 16)

typedef _Float16       f16x4  __attribute__((ext_vector_type(4)));
typedef float          f32x4  __attribute__((ext_vector_type(4)));
typedef unsigned       u32x2v __attribute__((ext_vector_type(2)));
typedef __fp16         pk2    __attribute__((ext_vector_type(2)));

__device__ __forceinline__ float frcp(float x){ return __builtin_amdgcn_rcpf(x); }
__device__ __forceinline__ float frsq(float x){ return __builtin_amdgcn_rsqf(x); }

// wave-local LDS ordering fence (all LDS is wave-private; rule #18 fence pair)
__device__ __forceinline__ void wave_fence(){
    asm volatile("s_waitcnt lgkmcnt(0)" ::: "memory");
    __builtin_amdgcn_sched_barrier(0);
}

__device__ __forceinline__ unsigned packrtz(float a, float b){
    pk2 h = __builtin_amdgcn_cvt_pkrtz(a, b);
    union { pk2 h; unsigned u; } u; u.h = h; return u.u;
}
__device__ __forceinline__ float ftanh(float x){
    x = fminf(15.0f, fmaxf(-15.0f, x));
    float e = __expf(2.0f * x);
    return (e - 1.0f) * frcp(e + 1.0f);
}
template<int NN>
__device__ __forceinline__ void softmax_scale(float (&v)[NN], float gate){
    float mx = v[0];
#pragma unroll
    for (int j = 1; j < NN; ++j) mx = fmaxf(mx, v[j]);
    float s = 0.0f;
#pragma unroll
    for (int j = 0; j < NN; ++j){ v[j] = __expf(v[j] - mx); s += v[j]; }
    float r = frcp(s) * gate;
#pragma unroll
    for (int j = 0; j < NN; ++j) v[j] *= r;
}

union Frag2 { u32x2v u2; unsigned u[2]; f16x4 f; };

__device__ __forceinline__ f32x4 mfma16(f16x4 a, f16x4 b, f32x4 c){
    return __builtin_amdgcn_mfma_f32_16x16x16f16(a, b, c, 0, 0, 0);
}

// heads concat weight: col j of [Wm | Wh | Wc] (21 x 23)
__device__ __forceinline__ float headsW(const float* Wm, const float* Wh,
                                        const float* Wc, int k, int j){
    if (j < 13) return Wm[k*13 + j];
    if (j < 19) return Wh[k*6 + (j - 13)];
    if (j < 23) return Wc[k*4 + (j - 19)];
    return 0.0f;
}

// ---- fragment pack (HW-verified bytes; lane-symmetry -> valid W^T A-frags) ----
// fid: 0-7 enc1 | 8-23 enc2 | 24-27 enc3 | 28-31 dec1 | 32-35 dec2 | 36-39 heads
__global__ void pack_bfrags(const float* __restrict__ W1, const float* __restrict__ W2,
                            const float* __restrict__ W3, const float* __restrict__ Wd1,
                            const float* __restrict__ Wd2,
                            const float* __restrict__ Wm, const float* __restrict__ Wh,
                            const float* __restrict__ Wc, unsigned* __restrict__ ws)
{
    int t = blockIdx.x * blockDim.x + threadIdx.x;
    if (t >= NFRAG * 64) return;
    int fid = t >> 6, lane = t & 63;
    int g = lane >> 4, c = lane & 15;

    if (fid >= 36) {
        int e = fid - 36, ks16 = e >> 1, ct = e & 1;
        int col = ct*16 + c;
#pragma unroll
        for (int j = 0; j < 2; ++j) {
            int k0 = ks16*16 + g*4 + 2*j;
            float a = (k0     < SD && col < 23) ? headsW(Wm, Wh, Wc, k0,   col) : 0.0f;
            float b = (k0 + 1 < SD && col < 23) ? headsW(Wm, Wh, Wc, k0+1, col) : 0.0f;
            ws[fid*128 + lane*2 + j] = packrtz(a, b);
        }
        return;
    }

    const float* W; int ks16, ct, K, Ncol, ld;
    if (fid < 8)       { W = W1;  ks16 = fid >> 2;    ct = fid & 3;  K = 21; Ncol = 64; ld = 64; }
    else if (fid < 24) { int e = fid - 8;
                         W = W2;  ks16 = e >> 2;      ct = e & 3;    K = 64; Ncol = 64; ld = 64; }
    else if (fid < 28) { W = W3;  ks16 = fid - 24;    ct = 0;        K = 64; Ncol = 14; ld = 14; }
    else if (fid < 32) { W = Wd1; ks16 = 0;           ct = fid - 28; K = 14; Ncol = 64; ld = 64; }
    else               { W = Wd2; ks16 = fid - 32;    ct = 0;        K = 64; Ncol = 8;  ld = 8;  }
    int col = ct*16 + c;
#pragma unroll
    for (int j = 0; j < 2; ++j) {
        int k0 = ks16*16 + g*4 + 2*j;
        float a = (k0     < K && col < Ncol) ? W[k0*ld + col]     : 0.0f;
        float b = (k0 + 1 < K && col < Ncol) ? W[(k0+1)*ld + col] : 0.0f;
        ws[fid*128 + lane*2 + j] = packrtz(a, b);
    }
}

// Transposed chain (R21/R22), 64 rows/wave: 4 M-tiles through FULL-WIDTH phases
// (4 independent chains per phase for ILP), all-64-lane T1, load-per-use weights.
__global__ __launch_bounds__(256) void statenet_mfma11(
    const float* __restrict__ state,
    const unsigned* __restrict__ pw,
    const float* __restrict__ b1,
    const float* __restrict__ lng, const float* __restrict__ lnb,
    const float* __restrict__ b2,  const float* __restrict__ b3,
    const float* __restrict__ bd1, const float* __restrict__ bd2,
    const float* __restrict__ bm,  const float* __restrict__ bh,
    const float* __restrict__ bc,
    const float* __restrict__ psm, const float* __restrict__ psh,
    const float* __restrict__ psc,
    float* __restrict__ out, int N)
{
    __shared__ __align__(16) unsigned s_at[4*64*ATS];   // 20480 B: f16-pair staging /wave
    __shared__ __align__(16) float    s_lg[4*64*26];    // 26624 B: raw state -> logits /wave

    const int tid = threadIdx.x;
    const int w  = tid >> 6, l = tid & 63;
    const int cl = l & 15,  g = l >> 4;
    const long long rowbase = (long long)blockIdx.x * 256 + w * 64;

    unsigned* at  = s_at + w * 64 * ATS;
    float*    slg = s_lg + w * 64 * 26;

    const u32x2v* BF2 = reinterpret_cast<const u32x2v*>(pw);
    const f32x4 vzero = {0.0f, 0.0f, 0.0f, 0.0f};

    // ============ T1-A0: coalesced stage of 64 rows (1344 f32 = 336 float4) ============
    {
        const float4* g4 = reinterpret_cast<const float4*>(state + rowbase * SD);
        float4* r4 = reinterpret_cast<float4*>(slg);
#pragma unroll
        for (int i = 0; i < 6; ++i) {
            int idx = l + i * 64;
            if (idx < 336) r4[idx] = g4[idx];
        }
    }
    wave_fence();                                      // F0: raw state ready

    // ============ T1-A: normalize + stage ns pairs — ALL 64 lanes, 1 row each ============
    float ns[SD];
    {
        const float* p = slg + l * SD;                 // stride-21 (odd): conflict-free
#pragma unroll
        for (int k = 0; k < SD; ++k) ns[k] = p[k];

        ns[0]  *= (1.0f / 3.0f);
        ns[1]  *= (1.0f / 3.0f);
        ns[17] *= 0.5f;
        ns[18] *= 0.25f;
        ns[19]  = fminf(fmaxf(ns[19], 0.0f), 2.0f) * 0.5f;

        const int base = l * ATS;
#pragma unroll
        for (int kk = 0; kk < 10; ++kk) at[base + kk] = packrtz(ns[2*kk], ns[2*kk+1]);
        at[base + 10] = packrtz(ns[20], 0.0f);
#pragma unroll
        for (int kk = 11; kk < 16; ++kk) at[base + kk] = 0u;
    }
    wave_fence();                                      // F1: at(ns) ready

    // ============ heads: logits^T = heads^T @ ns^T (4 M-tiles) ============
    {
        Frag2 aN[4][2];
#pragma unroll
        for (int M = 0; M < 4; ++M)
#pragma unroll
            for (int ks = 0; ks < 2; ++ks)
                aN[M][ks].u2 = *reinterpret_cast<const u32x2v*>(&at[(M*16 + cl)*ATS + ks*8 + 2*g]);
        f32x4 hl[2][4];
#pragma unroll
        for (int ct = 0; ct < 2; ++ct)
#pragma unroll
            for (int M = 0; M < 4; ++M) hl[ct][M] = vzero;
#pragma unroll
        for (int ct = 0; ct < 2; ++ct)
#pragma unroll
            for (int ks = 0; ks < 2; ++ks) {
                Frag2 wf; wf.u2 = BF2[(36 + ks*2 + ct)*64 + l];
#pragma unroll
                for (int M = 0; M < 4; ++M)
                    hl[ct][M] = mfma16(wf.f, aN[M][ks].f, hl[ct][M]);
            }
#pragma unroll
        for (int M = 0; M < 4; ++M) {
            float* p0 = &slg[(M*16 + cl)*26 + 4*g];
            reinterpret_cast<float2*>(p0)[0] = make_float2(hl[0][M][0], hl[0][M][1]);
            reinterpret_cast<float2*>(p0)[1] = make_float2(hl[0][M][2], hl[0][M][3]);
            if (g < 2) {
                float* p1 = &slg[(M*16 + cl)*26 + 16 + 4*g];
                reinterpret_cast<float2*>(p1)[0] = make_float2(hl[1][M][0], hl[1][M][1]);
                reinterpret_cast<float2*>(p1)[1] = make_float2(hl[1][M][2], hl[1][M][3]);
            }
        }
    }
    wave_fence();                                      // F2: logits ready

    // ============ T1-B: softmax + head stores + attended — ALL 64 lanes ============
    {
        const long long row = rowbase + l;
        float lg[24];
#pragma unroll
        for (int i = 0; i < 12; ++i) {
            float2 v = *reinterpret_cast<const float2*>(&slg[l*26 + 2*i]);
            lg[2*i] = v.x; lg[2*i+1] = v.y;
        }
        float m[13], hv[6], cv[4];
#pragma unroll
        for (int j = 0; j < 13; ++j) m[j]  = lg[j]      + bm[j];
#pragma unroll
        for (int j = 0; j < 6;  ++j) hv[j] = lg[13 + j] + bh[j];
#pragma unroll
        for (int j = 0; j < 4;  ++j) cv[j] = lg[19 + j] + bc[j];

        const float gm = 2.0f * frcp(1.0f + __expf(-psm[0]));
        const float gh = 2.0f * frcp(1.0f + __expf(-psh[0]));
        const float gc = 2.0f * frcp(1.0f + __expf(-psc[0]));
        softmax_scale<13>(m,  gm);
        softmax_scale<6 >(hv, gh);
        softmax_scale<4 >(cv, gc);

        {
            float* pm = out + (long long)22 * N + row * 13;
#pragma unroll
            for (int j = 0; j < 13; ++j) pm[j] = m[j];
            float* ph = out + (long long)35 * N + row * 6;
#pragma unroll
            for (int j = 0; j < 3; ++j)
                reinterpret_cast<float2*>(ph)[j] = make_float2(hv[2*j], hv[2*j+1]);
            float* pc = out + (long long)41 * N + row * 4;
            reinterpret_cast<float4*>(pc)[0] = make_float4(cv[0], cv[1], cv[2], cv[3]);
        }

        constexpr int EIDX[SD] = {0,1,2,3,4,4,5,5,5,6,6,6,7,7,8,9,9,10,10,11,12};
        float atv[SD];
#pragma unroll
        for (int k = 0; k < SD; ++k) atv[k] = ns[k] * m[EIDX[k]];
        const int base = l * ATS;
#pragma unroll
        for (int kk = 0; kk < 10; ++kk) at[base + kk] = packrtz(atv[2*kk], atv[2*kk+1]);
        at[base + 10] = packrtz(atv[20], 0.0f);
        // pads 11..15 still zero from T1-A
    }
    wave_fence();                                      // F3: at(attended) ready

    // ============ enc1: h1^T = W1^T @ at^T, LN+tanh in-register (4 M-tiles) ============
    Frag2 aA[4][2];
#pragma unroll
    for (int M = 0; M < 4; ++M)
#pragma unroll
        for (int ks = 0; ks < 2; ++ks)
            aA[M][ks].u2 = *reinterpret_cast<const u32x2v*>(&at[(M*16 + cl)*ATS + ks*8 + 2*g]);

    f32x4 D1[4][4];                                    // [f][M]
#pragma unroll
    for (int f = 0; f < 4; ++f)
#pragma unroll
        for (int M = 0; M < 4; ++M) D1[f][M] = vzero;
#pragma unroll
    for (int f = 0; f < 4; ++f)
#pragma unroll
        for (int ks = 0; ks < 2; ++ks) {
            Frag2 wf; wf.u2 = BF2[(ks*4 + f)*64 + l];
#pragma unroll
            for (int M = 0; M < 4; ++M)
                D1[f][M] = mfma16(wf.f, aA[M][ks].f, D1[f][M]);
        }

    float4 b1q[4], lgq[4], lbq[4];
#pragma unroll
    for (int f = 0; f < 4; ++f) {
        b1q[f] = *reinterpret_cast<const float4*>(&b1[f*16 + 4*g]);
        lgq[f] = *reinterpret_cast<const float4*>(&lng[f*16 + 4*g]);
        lbq[f] = *reinterpret_cast<const float4*>(&lnb[f*16 + 4*g]);
    }

    Frag2 B1[4][4];                                    // [M][f]
#pragma unroll
    for (int M = 0; M < 4; ++M) {
        float s = 0.0f, ss = 0.0f;
#pragma unroll
        for (int f = 0; f < 4; ++f) {
            float bb[4] = {b1q[f].x, b1q[f].y, b1q[f].z, b1q[f].w};
#pragma unroll
            for (int q = 0; q < 4; ++q) {
                float v = D1[f][M][q] + bb[q];
                D1[f][M][q] = v;
                s += v; ss = fmaf(v, v, ss);
            }
        }
        s  += __shfl_xor(s, 16);  s  += __shfl_xor(s, 32);
        ss += __shfl_xor(ss, 16); ss += __shfl_xor(ss, 32);
        float mu   = s * (1.0f/64.0f);
        float var  = ss * (1.0f/64.0f) - mu*mu;
        float istd = frsq(var + 1e-5f);
#pragma unroll
        for (int f = 0; f < 4; ++f) {
            float gg[4] = {lgq[f].x, lgq[f].y, lgq[f].z, lgq[f].w};
            float be[4] = {lbq[f].x, lbq[f].y, lbq[f].z, lbq[f].w};
            float t0 = ftanh(fmaf((D1[f][M][0] - mu) * istd, gg[0], be[0]));
            float t1 = ftanh(fmaf((D1[f][M][1] - mu) * istd, gg[1], be[1]));
            float t2 = ftanh(fmaf((D1[f][M][2] - mu) * istd, gg[2], be[2]));
            float t3 = ftanh(fmaf((D1[f][M][3] - mu) * istd, gg[3], be[3]));
            B1[M][f].u[0] = packrtz(t0, t1);
            B1[M][f].u[1] = packrtz(t2, t3);
        }
    }

    // ============ enc2: h2^T = W2^T @ h1^T (+relu) ============
    f32x4 D2[4][4];                                    // [f2][M]
#pragma unroll
    for (int f2 = 0; f2 < 4; ++f2)
#pragma unroll
        for (int M = 0; M < 4; ++M) D2[f2][M] = vzero;
#pragma unroll
    for (int f2 = 0; f2 < 4; ++f2)
#pragma unroll
        for (int f = 0; f < 4; ++f) {
            Frag2 wf; wf.u2 = BF2[(8 + f*4 + f2)*64 + l];
#pragma unroll
            for (int M = 0; M < 4; ++M)
                D2[f2][M] = mfma16(wf.f, B1[M][f].f, D2[f2][M]);
        }
    Frag2 B2[4][4];                                    // [M][f2]
#pragma unroll
    for (int f2 = 0; f2 < 4; ++f2) {
        float4 bq = *reinterpret_cast<const float4*>(&b2[f2*16 + 4*g]);
        float bb[4] = {bq.x, bq.y, bq.z, bq.w};
#pragma unroll
        for (int M = 0; M < 4; ++M) {
            float t0 = fmaxf(D2[f2][M][0] + bb[0], 0.0f);
            float t1 = fmaxf(D2[f2][M][1] + bb[1], 0.0f);
            float t2 = fmaxf(D2[f2][M][2] + bb[2], 0.0f);
            float t3 = fmaxf(D2[f2][M][3] + bb[3], 0.0f);
            B2[M][f2].u[0] = packrtz(t0, t1);
            B2[M][f2].u[1] = packrtz(t2, t3);
        }
    }

    // ============ enc3: lat^T = W3^T @ h2^T (store + pack) ============
    float b3v[4];
#pragma unroll
    for (int q = 0; q < 4; ++q) {
        int j = 4*g + q;
        b3v[q] = (j < LT) ? b3[j] : 0.0f;
    }
    f32x4 a3[4];
#pragma unroll
    for (int M = 0; M < 4; ++M) a3[M] = vzero;
#pragma unroll
    for (int f = 0; f < 4; ++f) {
        Frag2 wf; wf.u2 = BF2[(24 + f)*64 + l];
#pragma unroll
        for (int M = 0; M < 4; ++M)
            a3[M] = mfma16(wf.f, B2[M][f].f, a3[M]);
    }
    Frag2 B3[4];
#pragma unroll
    for (int M = 0; M < 4; ++M) {
        float lv[4];
#pragma unroll
        for (int q = 0; q < 4; ++q)
            lv[q] = (4*g + q < LT) ? (a3[M][q] + b3v[q]) : 0.0f;
        {
            float* pl = out + (long long)8 * N + (rowbase + M*16 + cl) * 14 + 4*g;
            if (g < 3) {
                reinterpret_cast<float2*>(pl)[0] = make_float2(lv[0], lv[1]);
                reinterpret_cast<float2*>(pl)[1] = make_float2(lv[2], lv[3]);
            } else {
                reinterpret_cast<float2*>(pl)[0] = make_float2(lv[0], lv[1]);
            }
        }
        B3[M].u[0] = packrtz(lv[0], lv[1]);
        B3[M].u[1] = packrtz(lv[2], lv[3]);
    }

    // ============ dec1: d1^T = Wd1^T @ lat^T (+relu) ============
    f32x4 D4[4][4];                                    // [f][M]
#pragma unroll
    for (int f = 0; f < 4; ++f)
#pragma unroll
        for (int M = 0; M < 4; ++M) D4[f][M] = vzero;
#pragma unroll
    for (int f = 0; f < 4; ++f) {
        Frag2 wf; wf.u2 = BF2[(28 + f)*64 + l];
#pragma unroll
        for (int M = 0; M < 4; ++M)
            D4[f][M] = mfma16(wf.f, B3[M].f, D4[f][M]);
    }
    Frag2 B4[4][4];                                    // [M][f]
#pragma unroll
    for (int f = 0; f < 4; ++f) {
        float4 bq = *reinterpret_cast<const float4*>(&bd1[f*16 + 4*g]);
        float bb[4] = {bq.x, bq.y, bq.z, bq.w};
#pragma unroll
        for (int M = 0; M < 4; ++M) {
            float t0 = fmaxf(D4[f][M][0] + bb[0], 0.0f);
            float t1 = fmaxf(D4[f][M][1] + bb[1], 0.0f);
            float t2 = fmaxf(D4[f][M][2] + bb[2], 0.0f);
            float t3 = fmaxf(D4[f][M][3] + bb[3], 0.0f);
            B4[M][f].u[0] = packrtz(t0, t1);
            B4[M][f].u[1] = packrtz(t2, t3);
        }
    }

    // ============ dec2: corr^T = Wd2^T @ d1^T -> tanh -> float4 stores ============
    f32x4 a5[4];
#pragma unroll
    for (int M = 0; M < 4; ++M) a5[M] = vzero;
#pragma unroll
    for (int f = 0; f < 4; ++f) {
        Frag2 wf; wf.u2 = BF2[(32 + f)*64 + l];
#pragma unroll
        for (int M = 0; M < 4; ++M)
            a5[M] = mfma16(wf.f, B4[M][f].f, a5[M]);
    }
#pragma unroll
    for (int M = 0; M < 4; ++M) {
        if (g < 2) {
            float4 bq = *reinterpret_cast<const float4*>(&bd2[4*g]);
            float* pc = out + (rowbase + M*16 + cl) * 8 + 4*g;   // 16B aligned
            reinterpret_cast<float4*>(pc)[0] =
                make_float4(ftanh(a5[M][0] + bq.x), ftanh(a5[M][1] + bq.y),
                            ftanh(a5[M][2] + bq.z), ftanh(a5[M][3] + bq.w));
        }
    }
}

extern "C" void kernel_launch(void* const* d_in, const int* in_sizes, int n_in,
                              void* d_out, int out_size, void* d_ws, size_t ws_size,
                              hipStream_t stream)
{
    const float* state = (const float*)d_in[0];
    const float* W1   = (const float*)d_in[1];
    const float* b1   = (const float*)d_in[2];
    const float* lng  = (const float*)d_in[3];
    const float* lnb  = (const float*)d_in[4];
    const float* W2   = (const float*)d_in[5];
    const float* b2   = (const float*)d_in[6];
    const float* W3   = (const float*)d_in[7];
    const float* b3   = (const float*)d_in[8];
    const float* Wd1  = (const float*)d_in[9];
    const float* bd1  = (const float*)d_in[10];
    const float* Wd2  = (const float*)d_in[11];
    const float* bd2  = (const float*)d_in[12];
    const float* Wm   = (const float*)d_in[13];
    const float* bm   = (const float*)d_in[14];
    const float* Wh   = (const float*)d_in[15];
    const float* bh   = (const float*)d_in[16];
    const float* Wc   = (const float*)d_in[17];
    const float* bc   = (const float*)d_in[18];
    const float* psm  = (const float*)d_in[19];
    const float* psh  = (const float*)d_in[20];
    const float* psc  = (const float*)d_in[21];

    unsigned* pw = (unsigned*)d_ws;

    hipLaunchKernelGGL(pack_bfrags, dim3((NFRAG*64 + 255)/256), dim3(256), 0, stream,
                       W1, W2, W3, Wd1, Wd2, Wm, Wh, Wc, pw);

    const int N = in_sizes[0] / SD;              // 1048576
    hipLaunchKernelGGL(statenet_mfma11, dim3(N / 256), dim3(256), 0, stream,
                       state, pw, b1, lng, lnb, b2, b3, bd1, bd2,
                       bm, bh, bc, psm, psh, psc,
                       (float*)d_out, N);
}

// Round 25
// 120.539 us; speedup vs baseline: 1.0410x; 1.0410x over previous
//
#include <hip/hip_runtime.h>

static constexpr int SD = 21, HD = 64, LT = 14;
static constexpr int NFRAG = 40;     // 36 MLP frags + 4 head frags (fid 36-39)

typedef _Float16       f16x4  __attribute__((ext_vector_type(4)));
typedef float          f32x4  __attribute__((ext_vector_type(4)));
typedef unsigned       u32x2v __attribute__((ext_vector_type(2)));
typedef __fp16         pk2    __attribute__((ext_vector_type(2)));

__device__ __forceinline__ float frcp(float x){ return __builtin_amdgcn_rcpf(x); }
__device__ __forceinline__ float frsq(float x){ return __builtin_amdgcn_rsqf(x); }

// wave-local LDS ordering fence (all LDS is wave-private; rule #18 fence pair)
__device__ __forceinline__ void wave_fence(){
    asm volatile("s_waitcnt lgkmcnt(0)" ::: "memory");
    __builtin_amdgcn_sched_barrier(0);
}

__device__ __forceinline__ unsigned packrtz(float a, float b){
    pk2 h = __builtin_amdgcn_cvt_pkrtz(a, b);
    union { pk2 h; unsigned u; } u; u.h = h; return u.u;
}
__device__ __forceinline__ float ftanh(float x){
    x = fminf(15.0f, fmaxf(-15.0f, x));
    float e = __expf(2.0f * x);
    return (e - 1.0f) * frcp(e + 1.0f);
}
template<int NN>
__device__ __forceinline__ void softmax_scale(float (&v)[NN], float gate){
    float mx = v[0];
#pragma unroll
    for (int j = 1; j < NN; ++j) mx = fmaxf(mx, v[j]);
    float s = 0.0f;
#pragma unroll
    for (int j = 0; j < NN; ++j){ v[j] = __expf(v[j] - mx); s += v[j]; }
    float r = frcp(s) * gate;
#pragma unroll
    for (int j = 0; j < NN; ++j) v[j] *= r;
}

union Frag2 { u32x2v u2; unsigned u[2]; f16x4 f; };

__device__ __forceinline__ f32x4 mfma16(f16x4 a, f16x4 b, f32x4 c){
    return __builtin_amdgcn_mfma_f32_16x16x16f16(a, b, c, 0, 0, 0);
}

// heads concat weight: col j of [Wm | Wh | Wc] (21 x 23)
__device__ __forceinline__ float headsW(const float* Wm, const float* Wh,
                                        const float* Wc, int k, int j){
    if (j < 13) return Wm[k*13 + j];
    if (j < 19) return Wh[k*6 + (j - 13)];
    if (j < 23) return Wc[k*4 + (j - 19)];
    return 0.0f;
}

// ---- fragment pack (HW-verified bytes; lane-symmetry -> valid W^T A-frags) ----
// fid: 0-7 enc1 | 8-23 enc2 | 24-27 enc3 | 28-31 dec1 | 32-35 dec2 | 36-39 heads
__global__ void pack_bfrags(const float* __restrict__ W1, const float* __restrict__ W2,
                            const float* __restrict__ W3, const float* __restrict__ Wd1,
                            const float* __restrict__ Wd2,
                            const float* __restrict__ Wm, const float* __restrict__ Wh,
                            const float* __restrict__ Wc, unsigned* __restrict__ ws)
{
    int t = blockIdx.x * blockDim.x + threadIdx.x;
    if (t >= NFRAG * 64) return;
    int fid = t >> 6, lane = t & 63;
    int g = lane >> 4, c = lane & 15;

    if (fid >= 36) {
        int e = fid - 36, ks16 = e >> 1, ct = e & 1;
        int col = ct*16 + c;
#pragma unroll
        for (int j = 0; j < 2; ++j) {
            int k0 = ks16*16 + g*4 + 2*j;
            float a = (k0     < SD && col < 23) ? headsW(Wm, Wh, Wc, k0,   col) : 0.0f;
            float b = (k0 + 1 < SD && col < 23) ? headsW(Wm, Wh, Wc, k0+1, col) : 0.0f;
            ws[fid*128 + lane*2 + j] = packrtz(a, b);
        }
        return;
    }

    const float* W; int ks16, ct, K, Ncol, ld;
    if (fid < 8)       { W = W1;  ks16 = fid >> 2;    ct = fid & 3;  K = 21; Ncol = 64; ld = 64; }
    else if (fid < 24) { int e = fid - 8;
                         W = W2;  ks16 = e >> 2;      ct = e & 3;    K = 64; Ncol = 64; ld = 64; }
    else if (fid < 28) { W = W3;  ks16 = fid - 24;    ct = 0;        K = 64; Ncol = 14; ld = 14; }
    else if (fid < 32) { W = Wd1; ks16 = 0;           ct = fid - 28; K = 14; Ncol = 64; ld = 64; }
    else               { W = Wd2; ks16 = fid - 32;    ct = 0;        K = 64; Ncol = 8;  ld = 8;  }
    int col = ct*16 + c;
#pragma unroll
    for (int j = 0; j < 2; ++j) {
        int k0 = ks16*16 + g*4 + 2*j;
        float a = (k0     < K && col < Ncol) ? W[k0*ld + col]     : 0.0f;
        float b = (k0 + 1 < K && col < Ncol) ? W[(k0+1)*ld + col] : 0.0f;
        ws[fid*128 + lane*2 + j] = packrtz(a, b);
    }
}

// Transposed chain (R21): every layer computes Y^T = W^T @ X^T; D-layout feeds next B.
// Coalesced input staging through the s_lg overlay (raw-state role -> logits role).
__global__ __launch_bounds__(256) void statenet_mfma9(
    const float* __restrict__ state,
    const unsigned* __restrict__ pw,
    const float* __restrict__ b1,
    const float* __restrict__ lng, const float* __restrict__ lnb,
    const float* __restrict__ b2,  const float* __restrict__ b3,
    const float* __restrict__ bd1, const float* __restrict__ bd2,
    const float* __restrict__ bm,  const float* __restrict__ bh,
    const float* __restrict__ bc,
    const float* __restrict__ psm, const float* __restrict__ psh,
    const float* __restrict__ psc,
    float* __restrict__ out, int N)
{
    __shared__ __align__(16) unsigned s_at[4*1152];   // at: [32][36] u32 f16-pairs /wave
    __shared__ __align__(16) float    s_lg[4*832];    // overlay: raw state (672 f32) -> logits [32][26]

    const int tid = threadIdx.x;
    const int w  = tid >> 6, l = tid & 63;
    const int cl = l & 15,  g = l >> 4;
    const long long rowbase = (long long)blockIdx.x * 128 + w * 32;

    unsigned* at  = s_at + w * 1152;
    float*    slg = s_lg + w * 832;

    const u32x2v* BF2 = reinterpret_cast<const u32x2v*>(pw);
    const f32x4 vzero = {0.0f, 0.0f, 0.0f, 0.0f};

    // ============ T1-A0: COALESCED stage of this wave's 32 rows into slg(raw) ============
    {
        const float4* g4 = reinterpret_cast<const float4*>(state + rowbase * SD);
        float4* r4 = reinterpret_cast<float4*>(slg);
#pragma unroll
        for (int i = 0; i < 3; ++i) {
            int idx = l + i * 64;
            if (idx < 168) r4[idx] = g4[idx];
        }
    }
    wave_fence();                                      // F0: raw state ready

    // ============ T1-A: normalize + stage ns pairs (lanes 0..31) ============
    float ns[SD];
    if (l < 32) {
        const float* p = slg + l * SD;                 // stride-21: conflict-free
#pragma unroll
        for (int k = 0; k < SD; ++k) ns[k] = p[k];

        ns[0]  *= (1.0f / 3.0f);
        ns[1]  *= (1.0f / 3.0f);
        ns[17] *= 0.5f;
        ns[18] *= 0.25f;
        ns[19]  = fminf(fmaxf(ns[19], 0.0f), 2.0f) * 0.5f;

        const int base = l * 36;
#pragma unroll
        for (int kk = 0; kk < 10; ++kk) at[base + kk] = packrtz(ns[2*kk], ns[2*kk+1]);
        at[base + 10] = packrtz(ns[20], 0.0f);
#pragma unroll
        for (int kk = 11; kk < 16; ++kk) at[base + kk] = 0u;
    }
    wave_fence();                                      // F1: at(ns) ready; raw reads drained

    // ============ heads: logits^T = heads^T @ ns^T (writes slg -> logits role) ============
    {
        Frag2 aN[2][2];
#pragma unroll
        for (int m2 = 0; m2 < 2; ++m2)
#pragma unroll
            for (int ks = 0; ks < 2; ++ks)
                aN[m2][ks].u2 = *reinterpret_cast<const u32x2v*>(&at[(m2*16 + cl)*36 + ks*8 + 2*g]);
        f32x4 hl[2][2];
#pragma unroll
        for (int ct = 0; ct < 2; ++ct)
#pragma unroll
            for (int m2 = 0; m2 < 2; ++m2) hl[ct][m2] = vzero;
#pragma unroll
        for (int ct = 0; ct < 2; ++ct)
#pragma unroll
            for (int ks = 0; ks < 2; ++ks) {
                Frag2 wf; wf.u2 = BF2[(36 + ks*2 + ct)*64 + l];
#pragma unroll
                for (int m2 = 0; m2 < 2; ++m2)
                    hl[ct][m2] = mfma16(wf.f, aN[m2][ks].f, hl[ct][m2]);
            }
        // D: row = logit j (ct*16+4g+q), col = batch cl -> slg[(m2*16+cl)*26 + j]
#pragma unroll
        for (int m2 = 0; m2 < 2; ++m2) {
            float* p0 = &slg[(m2*16 + cl)*26 + 4*g];
            reinterpret_cast<float2*>(p0)[0] = make_float2(hl[0][m2][0], hl[0][m2][1]);
            reinterpret_cast<float2*>(p0)[1] = make_float2(hl[0][m2][2], hl[0][m2][3]);
            if (g < 2) {
                float* p1 = &slg[(m2*16 + cl)*26 + 16 + 4*g];
                reinterpret_cast<float2*>(p1)[0] = make_float2(hl[1][m2][0], hl[1][m2][1]);
                reinterpret_cast<float2*>(p1)[1] = make_float2(hl[1][m2][2], hl[1][m2][3]);
            }
        }
    }
    wave_fence();                                      // F2: logits ready

    // ============ T1-B: softmax + head stores + attended (lanes 0..31) ============
    if (l < 32) {
        const long long row = rowbase + l;
        float lg[24];
#pragma unroll
        for (int i = 0; i < 12; ++i) {
            float2 v = *reinterpret_cast<const float2*>(&slg[l*26 + 2*i]);
            lg[2*i] = v.x; lg[2*i+1] = v.y;
        }
        float m[13], hv[6], cv[4];
#pragma unroll
        for (int j = 0; j < 13; ++j) m[j]  = lg[j]      + bm[j];   // wave-uniform bias
#pragma unroll
        for (int j = 0; j < 6;  ++j) hv[j] = lg[13 + j] + bh[j];
#pragma unroll
        for (int j = 0; j < 4;  ++j) cv[j] = lg[19 + j] + bc[j];

        const float gm = 2.0f * frcp(1.0f + __expf(-psm[0]));
        const float gh = 2.0f * frcp(1.0f + __expf(-psh[0]));
        const float gc = 2.0f * frcp(1.0f + __expf(-psc[0]));
        softmax_scale<13>(m,  gm);
        softmax_scale<6 >(hv, gh);
        softmax_scale<4 >(cv, gc);

        {
            float* pm = out + (long long)22 * N + row * 13;
#pragma unroll
            for (int j = 0; j < 13; ++j) pm[j] = m[j];
            float* ph = out + (long long)35 * N + row * 6;
#pragma unroll
            for (int j = 0; j < 3; ++j)
                reinterpret_cast<float2*>(ph)[j] = make_float2(hv[2*j], hv[2*j+1]);
            float* pc = out + (long long)41 * N + row * 4;
            reinterpret_cast<float4*>(pc)[0] = make_float4(cv[0], cv[1], cv[2], cv[3]);
        }

        constexpr int EIDX[SD] = {0,1,2,3,4,4,5,5,5,6,6,6,7,7,8,9,9,10,10,11,12};
        float atv[SD];
#pragma unroll
        for (int k = 0; k < SD; ++k) atv[k] = ns[k] * m[EIDX[k]];
        const int base = l * 36;
#pragma unroll
        for (int kk = 0; kk < 10; ++kk) at[base + kk] = packrtz(atv[2*kk], atv[2*kk+1]);
        at[base + 10] = packrtz(atv[20], 0.0f);
        // pads 11..15 still zero
    }
    wave_fence();                                      // F3: at(attended) ready

    // ============ enc1: h1^T = W1^T @ at^T, LN+tanh in-register ============
    Frag2 aA[2][2];
#pragma unroll
    for (int m2 = 0; m2 < 2; ++m2)
#pragma unroll
        for (int ks = 0; ks < 2; ++ks)
            aA[m2][ks].u2 = *reinterpret_cast<const u32x2v*>(&at[(m2*16 + cl)*36 + ks*8 + 2*g]);

    f32x4 D1[4][2];
#pragma unroll
    for (int f = 0; f < 4; ++f)
#pragma unroll
        for (int m2 = 0; m2 < 2; ++m2) D1[f][m2] = vzero;
#pragma unroll
    for (int f = 0; f < 4; ++f)
#pragma unroll
        for (int ks = 0; ks < 2; ++ks) {
            Frag2 wf; wf.u2 = BF2[(ks*4 + f)*64 + l];
#pragma unroll
            for (int m2 = 0; m2 < 2; ++m2)
                D1[f][m2] = mfma16(wf.f, aA[m2][ks].f, D1[f][m2]);
        }

    float4 b1q[4], lgq[4], lbq[4];
#pragma unroll
    for (int f = 0; f < 4; ++f) {
        b1q[f] = *reinterpret_cast<const float4*>(&b1[f*16 + 4*g]);
        lgq[f] = *reinterpret_cast<const float4*>(&lng[f*16 + 4*g]);
        lbq[f] = *reinterpret_cast<const float4*>(&lnb[f*16 + 4*g]);
    }

    Frag2 B1[2][4];
#pragma unroll
    for (int m2 = 0; m2 < 2; ++m2) {
        float s = 0.0f, ss = 0.0f;
#pragma unroll
        for (int f = 0; f < 4; ++f) {
            float bb[4] = {b1q[f].x, b1q[f].y, b1q[f].z, b1q[f].w};
#pragma unroll
            for (int q = 0; q < 4; ++q) {
                float v = D1[f][m2][q] + bb[q];
                D1[f][m2][q] = v;
                s += v; ss = fmaf(v, v, ss);
            }
        }
        s  += __shfl_xor(s, 16);  s  += __shfl_xor(s, 32);
        ss += __shfl_xor(ss, 16); ss += __shfl_xor(ss, 32);
        float mu   = s * (1.0f/64.0f);
        float var  = ss * (1.0f/64.0f) - mu*mu;
        float istd = frsq(var + 1e-5f);
#pragma unroll
        for (int f = 0; f < 4; ++f) {
            float gg[4] = {lgq[f].x, lgq[f].y, lgq[f].z, lgq[f].w};
            float be[4] = {lbq[f].x, lbq[f].y, lbq[f].z, lbq[f].w};
            float t0 = ftanh(fmaf((D1[f][m2][0] - mu) * istd, gg[0], be[0]));
            float t1 = ftanh(fmaf((D1[f][m2][1] - mu) * istd, gg[1], be[1]));
            float t2 = ftanh(fmaf((D1[f][m2][2] - mu) * istd, gg[2], be[2]));
            float t3 = ftanh(fmaf((D1[f][m2][3] - mu) * istd, gg[3], be[3]));
            B1[m2][f].u[0] = packrtz(t0, t1);
            B1[m2][f].u[1] = packrtz(t2, t3);
        }
    }

    // ============ enc2: h2^T = W2^T @ h1^T (+relu) ============
    f32x4 D2[4][2];
#pragma unroll
    for (int f2 = 0; f2 < 4; ++f2)
#pragma unroll
        for (int m2 = 0; m2 < 2; ++m2) D2[f2][m2] = vzero;
#pragma unroll
    for (int f2 = 0; f2 < 4; ++f2)
#pragma unroll
        for (int f = 0; f < 4; ++f) {
            Frag2 wf; wf.u2 = BF2[(8 + f*4 + f2)*64 + l];
#pragma unroll
            for (int m2 = 0; m2 < 2; ++m2)
                D2[f2][m2] = mfma16(wf.f, B1[m2][f].f, D2[f2][m2]);
        }
    Frag2 B2[2][4];
#pragma unroll
    for (int f2 = 0; f2 < 4; ++f2) {
        float4 bq = *reinterpret_cast<const float4*>(&b2[f2*16 + 4*g]);
        float bb[4] = {bq.x, bq.y, bq.z, bq.w};
#pragma unroll
        for (int m2 = 0; m2 < 2; ++m2) {
            float t0 = fmaxf(D2[f2][m2][0] + bb[0], 0.0f);
            float t1 = fmaxf(D2[f2][m2][1] + bb[1], 0.0f);
            float t2 = fmaxf(D2[f2][m2][2] + bb[2], 0.0f);
            float t3 = fmaxf(D2[f2][m2][3] + bb[3], 0.0f);
            B2[m2][f2].u[0] = packrtz(t0, t1);
            B2[m2][f2].u[1] = packrtz(t2, t3);
        }
    }

    // ============ enc3: lat^T = W3^T @ h2^T (store + pack) ============
    float b3v[4];
#pragma unroll
    for (int q = 0; q < 4; ++q) {
        int j = 4*g + q;
        b3v[q] = (j < LT) ? b3[j] : 0.0f;
    }
    Frag2 B3[2];
#pragma unroll
    for (int m2 = 0; m2 < 2; ++m2) {
        f32x4 a3 = vzero;
#pragma unroll
        for (int f = 0; f < 4; ++f) {
            Frag2 wf; wf.u2 = BF2[(24 + f)*64 + l];
            a3 = mfma16(wf.f, B2[m2][f].f, a3);
        }
        float lv[4];
#pragma unroll
        for (int q = 0; q < 4; ++q)
            lv[q] = (4*g + q < LT) ? (a3[q] + b3v[q]) : 0.0f;
        {
            float* pl = out + (long long)8 * N + (rowbase + m2*16 + cl) * 14 + 4*g;
            if (g < 3) {
                reinterpret_cast<float2*>(pl)[0] = make_float2(lv[0], lv[1]);
                reinterpret_cast<float2*>(pl)[1] = make_float2(lv[2], lv[3]);
            } else {
                reinterpret_cast<float2*>(pl)[0] = make_float2(lv[0], lv[1]);
            }
        }
        B3[m2].u[0] = packrtz(lv[0], lv[1]);
        B3[m2].u[1] = packrtz(lv[2], lv[3]);
    }

    // ============ dec1: d1^T = Wd1^T @ lat^T (+relu) ============
    f32x4 D4[4][2];
#pragma unroll
    for (int f = 0; f < 4; ++f)
#pragma unroll
        for (int m2 = 0; m2 < 2; ++m2) D4[f][m2] = vzero;
#pragma unroll
    for (int f = 0; f < 4; ++f) {
        Frag2 wf; wf.u2 = BF2[(28 + f)*64 + l];
#pragma unroll
        for (int m2 = 0; m2 < 2; ++m2)
            D4[f][m2] = mfma16(wf.f, B3[m2].f, D4[f][m2]);
    }
    Frag2 B4[2][4];
#pragma unroll
    for (int f = 0; f < 4; ++f) {
        float4 bq = *reinterpret_cast<const float4*>(&bd1[f*16 + 4*g]);
        float bb[4] = {bq.x, bq.y, bq.z, bq.w};
#pragma unroll
        for (int m2 = 0; m2 < 2; ++m2) {
            float t0 = fmaxf(D4[f][m2][0] + bb[0], 0.0f);
            float t1 = fmaxf(D4[f][m2][1] + bb[1], 0.0f);
            float t2 = fmaxf(D4[f][m2][2] + bb[2], 0.0f);
            float t3 = fmaxf(D4[f][m2][3] + bb[3], 0.0f);
            B4[m2][f].u[0] = packrtz(t0, t1);
            B4[m2][f].u[1] = packrtz(t2, t3);
        }
    }

    // ============ dec2: corr^T = Wd2^T @ d1^T -> tanh -> float4 stores ============
#pragma unroll
    for (int m2 = 0; m2 < 2; ++m2) {
        f32x4 a5 = vzero;
#pragma unroll
        for (int f = 0; f < 4; ++f) {
            Frag2 wf; wf.u2 = BF2[(32 + f)*64 + l];
            a5 = mfma16(wf.f, B4[m2][f].f, a5);
        }
        if (g < 2) {
            float4 bq = *reinterpret_cast<const float4*>(&bd2[4*g]);
            float* pc = out + (rowbase + m2*16 + cl) * 8 + 4*g;   // 16B aligned
            reinterpret_cast<float4*>(pc)[0] =
                make_float4(ftanh(a5[0] + bq.x), ftanh(a5[1] + bq.y),
                            ftanh(a5[2] + bq.z), ftanh(a5[3] + bq.w));
        }
    }
}

extern "C" void kernel_launch(void* const* d_in, const int* in_sizes, int n_in,
                              void* d_out, int out_size, void* d_ws, size_t ws_size,
                              hipStream_t stream)
{
    const float* state = (const float*)d_in[0];
    const float* W1   = (const float*)d_in[1];
    const float* b1   = (const float*)d_in[2];
    const float* lng  = (const float*)d_in[3];
    const float* lnb  = (const float*)d_in[4];
    const float* W2   = (const float*)d_in[5];
    const float* b2   = (const float*)d_in[6];
    const float* W3   = (const float*)d_in[7];
    const float* b3   = (const float*)d_in[8];
    const float* Wd1  = (const float*)d_in[9];
    const float* bd1  = (const float*)d_in[10];
    const float* Wd2  = (const float*)d_in[11];
    const float* bd2  = (const float*)d_in[12];
    const float* Wm   = (const float*)d_in[13];
    const float* bm   = (const float*)d_in[14];
    const float* Wh   = (const float*)d_in[15];
    const float* bh   = (const float*)d_in[16];
    const float* Wc   = (const float*)d_in[17];
    const float* bc   = (const float*)d_in[18];
    const float* psm  = (const float*)d_in[19];
    const float* psh  = (const float*)d_in[20];
    const float* psc  = (const float*)d_in[21];

    unsigned* pw = (unsigned*)d_ws;

    hipLaunchKernelGGL(pack_bfrags, dim3((NFRAG*64 + 255)/256), dim3(256), 0, stream,
                       W1, W2, W3, Wd1, Wd2, Wm, Wh, Wc, pw);

    const int N = in_sizes[0] / SD;              // 1048576
    hipLaunchKernelGGL(statenet_mfma9, dim3(N / 128), dim3(256), 0, stream,
                       state, pw, b1, lng, lnb, b2, b3, bd1, bd2,
                       bm, bh, bc, psm, psh, psc,
                       (float*)d_out, N);
}

// Round 26
// 107.335 us; speedup vs baseline: 1.1691x; 1.1230x over previous
//
#include <hip/hip_runtime.h>

static constexpr int SD = 21, HD = 64, LT = 14;
static constexpr int NFRAG = 40;     // 36 MLP frags + 4 head frags (fid 36-39)
static constexpr int TPB   = 512;    // 8 waves/block: test per-CU workgroup-cap hypothesis
static constexpr int NW    = TPB / 64;

typedef _Float16       f16x4  __attribute__((ext_vector_type(4)));
typedef float          f32x4  __attribute__((ext_vector_type(4)));
typedef unsigned       u32x2v __attribute__((ext_vector_type(2)));
typedef __fp16         pk2    __attribute__((ext_vector_type(2)));

__device__ __forceinline__ float frcp(float x){ return __builtin_amdgcn_rcpf(x); }
__device__ __forceinline__ float frsq(float x){ return __builtin_amdgcn_rsqf(x); }

// wave-local LDS ordering fence (all LDS is wave-private; rule #18 fence pair)
__device__ __forceinline__ void wave_fence(){
    asm volatile("s_waitcnt lgkmcnt(0)" ::: "memory");
    __builtin_amdgcn_sched_barrier(0);
}

__device__ __forceinline__ unsigned packrtz(float a, float b){
    pk2 h = __builtin_amdgcn_cvt_pkrtz(a, b);
    union { pk2 h; unsigned u; } u; u.h = h; return u.u;
}
__device__ __forceinline__ float ftanh(float x){
    x = fminf(15.0f, fmaxf(-15.0f, x));
    float e = __expf(2.0f * x);
    return (e - 1.0f) * frcp(e + 1.0f);
}
template<int NN>
__device__ __forceinline__ void softmax_scale(float (&v)[NN], float gate){
    float mx = v[0];
#pragma unroll
    for (int j = 1; j < NN; ++j) mx = fmaxf(mx, v[j]);
    float s = 0.0f;
#pragma unroll
    for (int j = 0; j < NN; ++j){ v[j] = __expf(v[j] - mx); s += v[j]; }
    float r = frcp(s) * gate;
#pragma unroll
    for (int j = 0; j < NN; ++j) v[j] *= r;
}

union Frag2 { u32x2v u2; unsigned u[2]; f16x4 f; };

__device__ __forceinline__ f32x4 mfma16(f16x4 a, f16x4 b, f32x4 c){
    return __builtin_amdgcn_mfma_f32_16x16x16f16(a, b, c, 0, 0, 0);
}

// heads concat weight: col j of [Wm | Wh | Wc] (21 x 23)
__device__ __forceinline__ float headsW(const float* Wm, const float* Wh,
                                        const float* Wc, int k, int j){
    if (j < 13) return Wm[k*13 + j];
    if (j < 19) return Wh[k*6 + (j - 13)];
    if (j < 23) return Wc[k*4 + (j - 19)];
    return 0.0f;
}

// ---- fragment pack (HW-verified bytes; lane-symmetry -> valid W^T A-frags) ----
// fid: 0-7 enc1 | 8-23 enc2 | 24-27 enc3 | 28-31 dec1 | 32-35 dec2 | 36-39 heads
__global__ void pack_bfrags(const float* __restrict__ W1, const float* __restrict__ W2,
                            const float* __restrict__ W3, const float* __restrict__ Wd1,
                            const float* __restrict__ Wd2,
                            const float* __restrict__ Wm, const float* __restrict__ Wh,
                            const float* __restrict__ Wc, unsigned* __restrict__ ws)
{
    int t = blockIdx.x * blockDim.x + threadIdx.x;
    if (t >= NFRAG * 64) return;
    int fid = t >> 6, lane = t & 63;
    int g = lane >> 4, c = lane & 15;

    if (fid >= 36) {
        int e = fid - 36, ks16 = e >> 1, ct = e & 1;
        int col = ct*16 + c;
#pragma unroll
        for (int j = 0; j < 2; ++j) {
            int k0 = ks16*16 + g*4 + 2*j;
            float a = (k0     < SD && col < 23) ? headsW(Wm, Wh, Wc, k0,   col) : 0.0f;
            float b = (k0 + 1 < SD && col < 23) ? headsW(Wm, Wh, Wc, k0+1, col) : 0.0f;
            ws[fid*128 + lane*2 + j] = packrtz(a, b);
        }
        return;
    }

    const float* W; int ks16, ct, K, Ncol, ld;
    if (fid < 8)       { W = W1;  ks16 = fid >> 2;    ct = fid & 3;  K = 21; Ncol = 64; ld = 64; }
    else if (fid < 24) { int e = fid - 8;
                         W = W2;  ks16 = e >> 2;      ct = e & 3;    K = 64; Ncol = 64; ld = 64; }
    else if (fid < 28) { W = W3;  ks16 = fid - 24;    ct = 0;        K = 64; Ncol = 14; ld = 14; }
    else if (fid < 32) { W = Wd1; ks16 = 0;           ct = fid - 28; K = 14; Ncol = 64; ld = 64; }
    else               { W = Wd2; ks16 = fid - 32;    ct = 0;        K = 64; Ncol = 8;  ld = 8;  }
    int col = ct*16 + c;
#pragma unroll
    for (int j = 0; j < 2; ++j) {
        int k0 = ks16*16 + g*4 + 2*j;
        float a = (k0     < K && col < Ncol) ? W[k0*ld + col]     : 0.0f;
        float b = (k0 + 1 < K && col < Ncol) ? W[(k0+1)*ld + col] : 0.0f;
        ws[fid*128 + lane*2 + j] = packrtz(a, b);
    }
}

// Transposed chain (R22), 512-thread blocks: per-wave structure unchanged.
__global__ __launch_bounds__(TPB) void statenet_mfma12(
    const float* __restrict__ state,
    const unsigned* __restrict__ pw,
    const float* __restrict__ b1,
    const float* __restrict__ lng, const float* __restrict__ lnb,
    const float* __restrict__ b2,  const float* __restrict__ b3,
    const float* __restrict__ bd1, const float* __restrict__ bd2,
    const float* __restrict__ bm,  const float* __restrict__ bh,
    const float* __restrict__ bc,
    const float* __restrict__ psm, const float* __restrict__ psh,
    const float* __restrict__ psc,
    float* __restrict__ out, int N)
{
    __shared__ __align__(16) unsigned s_at[NW*1152];  // at: [32][36] u32 f16-pairs /wave
    __shared__ __align__(16) float    s_lg[NW*832];   // overlay: raw state -> logits [32][26]

    const int tid = threadIdx.x;
    const int w  = tid >> 6, l = tid & 63;
    const int cl = l & 15,  g = l >> 4;
    const long long rowbase = (long long)blockIdx.x * (NW*32) + w * 32;

    unsigned* at  = s_at + w * 1152;
    float*    slg = s_lg + w * 832;

    const u32x2v* BF2 = reinterpret_cast<const u32x2v*>(pw);
    const f32x4 vzero = {0.0f, 0.0f, 0.0f, 0.0f};

    // ============ T1-A0: COALESCED stage of this wave's 32 rows into slg(raw) ============
    {
        const float4* g4 = reinterpret_cast<const float4*>(state + rowbase * SD);
        float4* r4 = reinterpret_cast<float4*>(slg);
#pragma unroll
        for (int i = 0; i < 3; ++i) {
            int idx = l + i * 64;
            if (idx < 168) r4[idx] = g4[idx];
        }
    }
    wave_fence();                                      // F0: raw state ready

    // ============ T1-A: normalize + stage ns pairs (lanes 0..31) ============
    float ns[SD];
    if (l < 32) {
        const float* p = slg + l * SD;                 // stride-21: conflict-free
#pragma unroll
        for (int k = 0; k < SD; ++k) ns[k] = p[k];

        ns[0]  *= (1.0f / 3.0f);
        ns[1]  *= (1.0f / 3.0f);
        ns[17] *= 0.5f;
        ns[18] *= 0.25f;
        ns[19]  = fminf(fmaxf(ns[19], 0.0f), 2.0f) * 0.5f;

        const int base = l * 36;
#pragma unroll
        for (int kk = 0; kk < 10; ++kk) at[base + kk] = packrtz(ns[2*kk], ns[2*kk+1]);
        at[base + 10] = packrtz(ns[20], 0.0f);
#pragma unroll
        for (int kk = 11; kk < 16; ++kk) at[base + kk] = 0u;
    }
    wave_fence();                                      // F1: at(ns) ready; raw reads drained

    // ============ heads: logits^T = heads^T @ ns^T (writes slg -> logits role) ============
    {
        Frag2 aN[2][2];
#pragma unroll
        for (int m2 = 0; m2 < 2; ++m2)
#pragma unroll
            for (int ks = 0; ks < 2; ++ks)
                aN[m2][ks].u2 = *reinterpret_cast<const u32x2v*>(&at[(m2*16 + cl)*36 + ks*8 + 2*g]);
        f32x4 hl[2][2];
#pragma unroll
        for (int ct = 0; ct < 2; ++ct)
#pragma unroll
            for (int m2 = 0; m2 < 2; ++m2) hl[ct][m2] = vzero;
#pragma unroll
        for (int ct = 0; ct < 2; ++ct)
#pragma unroll
            for (int ks = 0; ks < 2; ++ks) {
                Frag2 wf; wf.u2 = BF2[(36 + ks*2 + ct)*64 + l];
#pragma unroll
                for (int m2 = 0; m2 < 2; ++m2)
                    hl[ct][m2] = mfma16(wf.f, aN[m2][ks].f, hl[ct][m2]);
            }
        // D: row = logit j (ct*16+4g+q), col = batch cl -> slg[(m2*16+cl)*26 + j]
#pragma unroll
        for (int m2 = 0; m2 < 2; ++m2) {
            float* p0 = &slg[(m2*16 + cl)*26 + 4*g];
            reinterpret_cast<float2*>(p0)[0] = make_float2(hl[0][m2][0], hl[0][m2][1]);
            reinterpret_cast<float2*>(p0)[1] = make_float2(hl[0][m2][2], hl[0][m2][3]);
            if (g < 2) {
                float* p1 = &slg[(m2*16 + cl)*26 + 16 + 4*g];
                reinterpret_cast<float2*>(p1)[0] = make_float2(hl[1][m2][0], hl[1][m2][1]);
                reinterpret_cast<float2*>(p1)[1] = make_float2(hl[1][m2][2], hl[1][m2][3]);
            }
        }
    }
    wave_fence();                                      // F2: logits ready

    // ============ T1-B: softmax + head stores + attended (lanes 0..31) ============
    if (l < 32) {
        const long long row = rowbase + l;
        float lg[24];
#pragma unroll
        for (int i = 0; i < 12; ++i) {
            float2 v = *reinterpret_cast<const float2*>(&slg[l*26 + 2*i]);
            lg[2*i] = v.x; lg[2*i+1] = v.y;
        }
        float m[13], hv[6], cv[4];
#pragma unroll
        for (int j = 0; j < 13; ++j) m[j]  = lg[j]      + bm[j];   // wave-uniform bias
#pragma unroll
        for (int j = 0; j < 6;  ++j) hv[j] = lg[13 + j] + bh[j];
#pragma unroll
        for (int j = 0; j < 4;  ++j) cv[j] = lg[19 + j] + bc[j];

        const float gm = 2.0f * frcp(1.0f + __expf(-psm[0]));
        const float gh = 2.0f * frcp(1.0f + __expf(-psh[0]));
        const float gc = 2.0f * frcp(1.0f + __expf(-psc[0]));
        softmax_scale<13>(m,  gm);
        softmax_scale<6 >(hv, gh);
        softmax_scale<4 >(cv, gc);

        {
            float* pm = out + (long long)22 * N + row * 13;
#pragma unroll
            for (int j = 0; j < 13; ++j) pm[j] = m[j];
            float* ph = out + (long long)35 * N + row * 6;
#pragma unroll
            for (int j = 0; j < 3; ++j)
                reinterpret_cast<float2*>(ph)[j] = make_float2(hv[2*j], hv[2*j+1]);
            float* pc = out + (long long)41 * N + row * 4;
            reinterpret_cast<float4*>(pc)[0] = make_float4(cv[0], cv[1], cv[2], cv[3]);
        }

        constexpr int EIDX[SD] = {0,1,2,3,4,4,5,5,5,6,6,6,7,7,8,9,9,10,10,11,12};
        float atv[SD];
#pragma unroll
        for (int k = 0; k < SD; ++k) atv[k] = ns[k] * m[EIDX[k]];
        const int base = l * 36;
#pragma unroll
        for (int kk = 0; kk < 10; ++kk) at[base + kk] = packrtz(atv[2*kk], atv[2*kk+1]);
        at[base + 10] = packrtz(atv[20], 0.0f);
        // pads 11..15 still zero
    }
    wave_fence();                                      // F3: at(attended) ready

    // ============ enc1: h1^T = W1^T @ at^T, LN+tanh in-register ============
    Frag2 aA[2][2];
#pragma unroll
    for (int m2 = 0; m2 < 2; ++m2)
#pragma unroll
        for (int ks = 0; ks < 2; ++ks)
            aA[m2][ks].u2 = *reinterpret_cast<const u32x2v*>(&at[(m2*16 + cl)*36 + ks*8 + 2*g]);

    f32x4 D1[4][2];
#pragma unroll
    for (int f = 0; f < 4; ++f)
#pragma unroll
        for (int m2 = 0; m2 < 2; ++m2) D1[f][m2] = vzero;
#pragma unroll
    for (int f = 0; f < 4; ++f)
#pragma unroll
        for (int ks = 0; ks < 2; ++ks) {
            Frag2 wf; wf.u2 = BF2[(ks*4 + f)*64 + l];
#pragma unroll
            for (int m2 = 0; m2 < 2; ++m2)
                D1[f][m2] = mfma16(wf.f, aA[m2][ks].f, D1[f][m2]);
        }

    float4 b1q[4], lgq[4], lbq[4];
#pragma unroll
    for (int f = 0; f < 4; ++f) {
        b1q[f] = *reinterpret_cast<const float4*>(&b1[f*16 + 4*g]);
        lgq[f] = *reinterpret_cast<const float4*>(&lng[f*16 + 4*g]);
        lbq[f] = *reinterpret_cast<const float4*>(&lnb[f*16 + 4*g]);
    }

    Frag2 B1[2][4];
#pragma unroll
    for (int m2 = 0; m2 < 2; ++m2) {
        float s = 0.0f, ss = 0.0f;
#pragma unroll
        for (int f = 0; f < 4; ++f) {
            float bb[4] = {b1q[f].x, b1q[f].y, b1q[f].z, b1q[f].w};
#pragma unroll
            for (int q = 0; q < 4; ++q) {
                float v = D1[f][m2][q] + bb[q];
                D1[f][m2][q] = v;
                s += v; ss = fmaf(v, v, ss);
            }
        }
        s  += __shfl_xor(s, 16);  s  += __shfl_xor(s, 32);
        ss += __shfl_xor(ss, 16); ss += __shfl_xor(ss, 32);
        float mu   = s * (1.0f/64.0f);
        float var  = ss * (1.0f/64.0f) - mu*mu;
        float istd = frsq(var + 1e-5f);
#pragma unroll
        for (int f = 0; f < 4; ++f) {
            float gg[4] = {lgq[f].x, lgq[f].y, lgq[f].z, lgq[f].w};
            float be[4] = {lbq[f].x, lbq[f].y, lbq[f].z, lbq[f].w};
            float t0 = ftanh(fmaf((D1[f][m2][0] - mu) * istd, gg[0], be[0]));
            float t1 = ftanh(fmaf((D1[f][m2][1] - mu) * istd, gg[1], be[1]));
            float t2 = ftanh(fmaf((D1[f][m2][2] - mu) * istd, gg[2], be[2]));
            float t3 = ftanh(fmaf((D1[f][m2][3] - mu) * istd, gg[3], be[3]));
            B1[m2][f].u[0] = packrtz(t0, t1);
            B1[m2][f].u[1] = packrtz(t2, t3);
        }
    }

    // ============ enc2: h2^T = W2^T @ h1^T (+relu) ============
    f32x4 D2[4][2];
#pragma unroll
    for (int f2 = 0; f2 < 4; ++f2)
#pragma unroll
        for (int m2 = 0; m2 < 2; ++m2) D2[f2][m2] = vzero;
#pragma unroll
    for (int f2 = 0; f2 < 4; ++f2)
#pragma unroll
        for (int f = 0; f < 4; ++f) {
            Frag2 wf; wf.u2 = BF2[(8 + f*4 + f2)*64 + l];
#pragma unroll
            for (int m2 = 0; m2 < 2; ++m2)
                D2[f2][m2] = mfma16(wf.f, B1[m2][f].f, D2[f2][m2]);
        }
    Frag2 B2[2][4];
#pragma unroll
    for (int f2 = 0; f2 < 4; ++f2) {
        float4 bq = *reinterpret_cast<const float4*>(&b2[f2*16 + 4*g]);
        float bb[4] = {bq.x, bq.y, bq.z, bq.w};
#pragma unroll
        for (int m2 = 0; m2 < 2; ++m2) {
            float t0 = fmaxf(D2[f2][m2][0] + bb[0], 0.0f);
            float t1 = fmaxf(D2[f2][m2][1] + bb[1], 0.0f);
            float t2 = fmaxf(D2[f2][m2][2] + bb[2], 0.0f);
            float t3 = fmaxf(D2[f2][m2][3] + bb[3], 0.0f);
            B2[m2][f2].u[0] = packrtz(t0, t1);
            B2[m2][f2].u[1] = packrtz(t2, t3);
        }
    }

    // ============ enc3: lat^T = W3^T @ h2^T (store + pack) ============
    float b3v[4];
#pragma unroll
    for (int q = 0; q < 4; ++q) {
        int j = 4*g + q;
        b3v[q] = (j < LT) ? b3[j] : 0.0f;
    }
    Frag2 B3[2];
#pragma unroll
    for (int m2 = 0; m2 < 2; ++m2) {
        f32x4 a3 = vzero;
#pragma unroll
        for (int f = 0; f < 4; ++f) {
            Frag2 wf; wf.u2 = BF2[(24 + f)*64 + l];
            a3 = mfma16(wf.f, B2[m2][f].f, a3);
        }
        float lv[4];
#pragma unroll
        for (int q = 0; q < 4; ++q)
            lv[q] = (4*g + q < LT) ? (a3[q] + b3v[q]) : 0.0f;
        {
            float* pl = out + (long long)8 * N + (rowbase + m2*16 + cl) * 14 + 4*g;
            if (g < 3) {
                reinterpret_cast<float2*>(pl)[0] = make_float2(lv[0], lv[1]);
                reinterpret_cast<float2*>(pl)[1] = make_float2(lv[2], lv[3]);
            } else {
                reinterpret_cast<float2*>(pl)[0] = make_float2(lv[0], lv[1]);
            }
        }
        B3[m2].u[0] = packrtz(lv[0], lv[1]);
        B3[m2].u[1] = packrtz(lv[2], lv[3]);
    }

    // ============ dec1: d1^T = Wd1^T @ lat^T (+relu) ============
    f32x4 D4[4][2];
#pragma unroll
    for (int f = 0; f < 4; ++f)
#pragma unroll
        for (int m2 = 0; m2 < 2; ++m2) D4[f][m2] = vzero;
#pragma unroll
    for (int f = 0; f < 4; ++f) {
        Frag2 wf; wf.u2 = BF2[(28 + f)*64 + l];
#pragma unroll
        for (int m2 = 0; m2 < 2; ++m2)
            D4[f][m2] = mfma16(wf.f, B3[m2].f, D4[f][m2]);
    }
    Frag2 B4[2][4];
#pragma unroll
    for (int f = 0; f < 4; ++f) {
        float4 bq = *reinterpret_cast<const float4*>(&bd1[f*16 + 4*g]);
        float bb[4] = {bq.x, bq.y, bq.z, bq.w};
#pragma unroll
        for (int m2 = 0; m2 < 2; ++m2) {
            float t0 = fmaxf(D4[f][m2][0] + bb[0], 0.0f);
            float t1 = fmaxf(D4[f][m2][1] + bb[1], 0.0f);
            float t2 = fmaxf(D4[f][m2][2] + bb[2], 0.0f);
            float t3 = fmaxf(D4[f][m2][3] + bb[3], 0.0f);
            B4[m2][f].u[0] = packrtz(t0, t1);
            B4[m2][f].u[1] = packrtz(t2, t3);
        }
    }

    // ============ dec2: corr^T = Wd2^T @ d1^T -> tanh -> float4 stores ============
#pragma unroll
    for (int m2 = 0; m2 < 2; ++m2) {
        f32x4 a5 = vzero;
#pragma unroll
        for (int f = 0; f < 4; ++f) {
            Frag2 wf; wf.u2 = BF2[(32 + f)*64 + l];
            a5 = mfma16(wf.f, B4[m2][f].f, a5);
        }
        if (g < 2) {
            float4 bq = *reinterpret_cast<const float4*>(&bd2[4*g]);
            float* pc = out + (rowbase + m2*16 + cl) * 8 + 4*g;   // 16B aligned
            reinterpret_cast<float4*>(pc)[0] =
                make_float4(ftanh(a5[0] + bq.x), ftanh(a5[1] + bq.y),
                            ftanh(a5[2] + bq.z), ftanh(a5[3] + bq.w));
        }
    }
}

extern "C" void kernel_launch(void* const* d_in, const int* in_sizes, int n_in,
                              void* d_out, int out_size, void* d_ws, size_t ws_size,
                              hipStream_t stream)
{
    const float* state = (const float*)d_in[0];
    const float* W1   = (const float*)d_in[1];
    const float* b1   = (const float*)d_in[2];
    const float* lng  = (const float*)d_in[3];
    const float* lnb  = (const float*)d_in[4];
    const float* W2   = (const float*)d_in[5];
    const float* b2   = (const float*)d_in[6];
    const float* W3   = (const float*)d_in[7];
    const float* b3   = (const float*)d_in[8];
    const float* Wd1  = (const float*)d_in[9];
    const float* bd1  = (const float*)d_in[10];
    const float* Wd2  = (const float*)d_in[11];
    const float* bd2  = (const float*)d_in[12];
    const float* Wm   = (const float*)d_in[13];
    const float* bm   = (const float*)d_in[14];
    const float* Wh   = (const float*)d_in[15];
    const float* bh   = (const float*)d_in[16];
    const float* Wc   = (const float*)d_in[17];
    const float* bc   = (const float*)d_in[18];
    const float* psm  = (const float*)d_in[19];
    const float* psh  = (const float*)d_in[20];
    const float* psc  = (const float*)d_in[21];

    unsigned* pw = (unsigned*)d_ws;

    hipLaunchKernelGGL(pack_bfrags, dim3((NFRAG*64 + 255)/256), dim3(256), 0, stream,
                       W1, W2, W3, Wd1, Wd2, Wm, Wh, Wc, pw);

    const int N = in_sizes[0] / SD;              // 1048576
    hipLaunchKernelGGL(statenet_mfma12, dim3(N / (NW*32)), dim3(TPB), 0, stream,
                       state, pw, b1, lng, lnb, b2, b3, bd1, bd2,
                       bm, bh, bc, psm, psh, psc,
                       (float*)d_out, N);
}